// Round 18
// baseline (142.739 us; speedup 1.0000x reference)
//
#include <hip/hip_runtime.h>
#include <hip/hip_bf16.h>

#define NN 4096
#define IC 128
#define OC 128
#define ED 16
#define EPB 32
#define NT 256
#define NSLOT 16
#define NBLK 512
#define NCPY 8

typedef __bf16 bf16x8 __attribute__((ext_vector_type(8)));
typedef float  f32x16 __attribute__((ext_vector_type(16)));

// raw barrier: drain LDS ops only; global loads/atomics stay in flight
#define BAR() do { asm volatile("s_waitcnt lgkmcnt(0)" ::: "memory"); \
    __builtin_amdgcn_s_barrier(); \
    __builtin_amdgcn_sched_barrier(0); } while (0)

__device__ __forceinline__ unsigned short bf16u(float f) {   // RNE f32->bf16
    unsigned int u = __float_as_uint(f);
    u = (u + 0x7FFFu + ((u >> 16) & 1u)) >> 16;
    return (unsigned short)u;
}
__device__ __forceinline__ float bf16tof(unsigned short h) {
    return __uint_as_float(((unsigned int)h) << 16);
}
__device__ __forceinline__ int swzk(int row) { return (row ^ (row >> 3)) & 7; }

// ---- Phase 1: xw1b = x@W1[:128]+b1; zero out; fused 8-replica hist ------
__global__ __launch_bounds__(128) void k_xw1(
    const float* __restrict__ x, const float* __restrict__ W1,
    const float* __restrict__ b1, const int* __restrict__ eidx,
    float* __restrict__ xw1b, float* __restrict__ out,
    int* __restrict__ hist8, int E)
{
    __shared__ float xs[8][IC];
    const int t = threadIdx.x;
    const int r0 = blockIdx.x * 8;
    #pragma unroll
    for (int r = 0; r < 8; ++r) xs[r][t] = x[(size_t)(r0 + r) * IC + t];

    const float4 z = make_float4(0.f, 0.f, 0.f, 0.f);
    float4* o4 = (float4*)out;
    o4[blockIdx.x * 256 + t]       = z;
    o4[blockIdx.x * 256 + 128 + t] = z;

    {   // fused hist; copy mapping matches k_scatter: edge e -> (e>>8)&7
        const int e0 = blockIdx.x * 512;
        #pragma unroll
        for (int j = 0; j < 4; ++j) {
            const int k = (2 * blockIdx.x + (j >> 1)) & (NCPY - 1);
            atomicAdd(&hist8[k * 4096 + eidx[E + e0 + t + j * 128]], 1);
        }
    }

    __syncthreads();
    float acc[8];
    const float bb = b1[t];
    #pragma unroll
    for (int r = 0; r < 8; ++r) acc[r] = bb;
    #pragma unroll 4
    for (int k = 0; k < IC; ++k) {
        const float w = W1[(size_t)k * OC + t];
        #pragma unroll
        for (int r = 0; r < 8; ++r) acc[r] = fmaf(xs[r][k], w, acc[r]);
    }
    #pragma unroll
    for (int r = 0; r < 8; ++r) xw1b[(size_t)(r0 + r) * OC + t] = acc[r];
}

// -------- scan (16-block A/B) + scatter (8-replica) -----------------------
__global__ __launch_bounds__(256) void k_scanA(
    const int* __restrict__ hist8, int* __restrict__ binloc,
    int* __restrict__ blocksum)
{
    __shared__ int sb[256];
    const int t = threadIdx.x;
    const int bin = blockIdx.x * 256 + t;
    int s = 0;
    #pragma unroll
    for (int k = 0; k < NCPY; ++k) s += hist8[k * 4096 + bin];
    sb[t] = s;
    __syncthreads();
    if (t == 0) {
        int a = 0;
        for (int i = 0; i < 256; ++i) { const int v = sb[i]; sb[i] = a; a += v; }
        blocksum[blockIdx.x] = a;
    }
    __syncthreads();
    binloc[bin] = sb[t];
}

__global__ __launch_bounds__(256) void k_scanB(
    const int* __restrict__ hist8, const int* __restrict__ binloc,
    const int* __restrict__ blocksum, int* __restrict__ cursor8,
    int* __restrict__ colstart, int E)
{
    __shared__ int baseL;
    const int t = threadIdx.x;
    if (t == 0) {
        int a = 0;
        for (int j = 0; j < (int)blockIdx.x; ++j) a += blocksum[j];
        baseL = a;
    }
    __syncthreads();
    const int bin = blockIdx.x * 256 + t;
    int off = baseL + binloc[bin];
    colstart[bin] = off;
    #pragma unroll
    for (int k = 0; k < NCPY; ++k) {
        cursor8[k * 4096 + bin] = off;
        off += hist8[k * 4096 + bin];
    }
    if (bin == 4095) colstart[4096] = E;
}

__global__ void k_scatter(const int* __restrict__ eidx, int* __restrict__ cursor8,
                          int2* __restrict__ csr, int E) {
    const int i = blockIdx.x * blockDim.x + threadIdx.x;
    const int k = blockIdx.x & (NCPY - 1);
    if (i < E) {
        const int row = eidx[i];
        const int col = eidx[E + i];
        const int pos = atomicAdd(&cursor8[k * 4096 + col], 1);
        csr[pos] = make_int2(row, col);
    }
}

// -------- Phase 2: fused-interval pipeline (PhaseA(ii+1) || PhaseB(ii)) --
// EPB=32, h1 double-buffered: ONE barrier per batch. Layer-1 (VALU) of the
// NEXT batch and layer-2 (MFMA+DS) of the CURRENT batch share a barrier
// interval -> pipes overlap (m233 2-phase-stall remedy; m114 co-issue).
// All proven parts kept: W2-in-regs 3-term split, swzk swizzle, persistent
// lacc + interior-col plain-store flush. LDS 54.3KB -> 2 blocks/CU.
__global__ __launch_bounds__(NT, 2) void k_edge11(
    const int2* __restrict__ csr, const float* __restrict__ eattr,
    const float* __restrict__ xw1b, const float* __restrict__ W1,
    const float* __restrict__ W2, const float* __restrict__ b2,
    const int* __restrict__ colstart, float* __restrict__ out, int E)
{
    extern __shared__ char smem[];
    char*   const h1hi = smem;                      // [2][32*256B] = 16KB
    char*   const h1lo = smem + 16384;              // 16KB
    float4* const eaL  = (float4*)(smem + 32768);   // [2][128] f4 = 4KB swz
    float4* const w1L  = (float4*)(smem + 36864);   // [512] f4 = 8KB
    float*  const lacc = (float*)(smem + 45056);    // [16][128] = 8KB
    int*    const srowL = (int*)(smem + 53248);     // [4][32]
    int*    const scolL = srowL + 128;              // [4][32]

    const int t   = threadIdx.x;
    const int l   = t & 63;
    const int wid = t >> 6;                 // 4 waves
    const int cg  = t & 15, eg = t >> 4;    // layer-1: 2e x 8c per thread
    const int c0  = cg << 3, e0 = eg << 1;
    const int sz  = (eg >> 2) & 3;          // = ((e0>>3)&3), same for e0,e0+1
    const int em  = t >> 2, q = t & 3;      // ea gather: t<128, 4 thr/edge
    const int esz = (em >> 3) & 3;
    const bool gth = (t < 128);

    const int lm  = l & 31;
    const int hi  = l >> 5;
    const int c2  = wid * 32 + lm;          // lane's output channel
    const int arow = lm;
    const int ak  = swzk(arow) << 4;

    w1L[t]      = ((const float4*)(W1 + (size_t)IC * OC))[t];
    w1L[t + NT] = ((const float4*)(W1 + (size_t)IC * OC))[t + NT];

    // W2 -> register hi/lo fragments (batch-invariant, 64 VGPR)
    bf16x8 w2h[8], w2l[8];
    #pragma unroll
    for (int s = 0; s < 8; ++s) {
        union { unsigned short us[8]; bf16x8 v; } Uh, Ul;
        #pragma unroll
        for (int j = 0; j < 8; ++j) {
            const float w = W2[(size_t)(s * 16 + hi * 8 + j) * OC + c2];
            const unsigned short h = bf16u(w);
            Uh.us[j] = h;
            Ul.us[j] = bf16u(w - bf16tof(h));
        }
        w2h[s] = Uh.v; w2l[s] = Ul.v;
    }
    const float b2s = b2[c2];

    #pragma unroll
    for (int i = 0; i < NSLOT * OC / NT; ++i) lacc[t + NT * i] = 0.f;

    const int nper = (E / EPB) / NBLK;      // 16 batches per block
    const int ibb  = blockIdx.x * nper;

    // ---- prologue: idx(0..2) -> LDS bufs 0..2 ----
    if (t < EPB) {
        #pragma unroll
        for (int b = 0; b < 3; ++b) {
            const int ib = (b < nper) ? b : (nper - 1);
            const int2 rc = csr[(size_t)(ibb + ib) * EPB + t];
            srowL[b * EPB + t] = rc.x;
            scolL[b * EPB + t] = rc.y;
        }
    }
    __syncthreads();
    const int colbase0 = scolL[0];

    // ea(0) -> eaL[0]; xw(0) -> regs
    float4 pA = make_float4(0.f, 0.f, 0.f, 0.f);
    if (gth) {
        const int r = srowL[em], c = scolL[em];
        pA = ((const float4*)(eattr + ((size_t)r * NN + c) * ED))[q];
        eaL[(em * 4 + q) ^ esz] = pA;
    }
    float4 xa[2], xb[2];
    #pragma unroll
    for (int ri = 0; ri < 2; ++ri) {
        const int row = srowL[e0 + ri];
        const float4* p = (const float4*)(xw1b + (size_t)row * OC + c0);
        xa[ri] = p[0]; xb[ri] = p[1];
    }
    __syncthreads();                        // eaL[0] visible

    // ---- PhaseA(0) -> h1 buf 0 (macro-free inline helper pattern) ----
    #define LAYER1(BUF) do { \
        float4 ha[2], hb[2]; \
        _Pragma("unroll") \
        for (int ri = 0; ri < 2; ++ri) { ha[ri] = xa[ri]; hb[ri] = xb[ri]; } \
        _Pragma("unroll") \
        for (int dc = 0; dc < 4; ++dc) { \
            float4 ev[2]; \
            _Pragma("unroll") \
            for (int ri = 0; ri < 2; ++ri) \
                ev[ri] = eaL[(BUF) * 128 + (((e0 + ri) * 4 + dc) ^ sz)]; \
            _Pragma("unroll") \
            for (int dd = 0; dd < 4; ++dd) { \
                const int d = dc * 4 + dd; \
                const float4 wA = w1L[d * 32 + cg * 2]; \
                const float4 wB = w1L[d * 32 + cg * 2 + 1]; \
                _Pragma("unroll") \
                for (int ri = 0; ri < 2; ++ri) { \
                    const float evd = (dd == 0) ? ev[ri].x : (dd == 1) ? ev[ri].y \
                                     : (dd == 2) ? ev[ri].z : ev[ri].w; \
                    ha[ri].x = fmaf(evd, wA.x, ha[ri].x); \
                    ha[ri].y = fmaf(evd, wA.y, ha[ri].y); \
                    ha[ri].z = fmaf(evd, wA.z, ha[ri].z); \
                    ha[ri].w = fmaf(evd, wA.w, ha[ri].w); \
                    hb[ri].x = fmaf(evd, wB.x, hb[ri].x); \
                    hb[ri].y = fmaf(evd, wB.y, hb[ri].y); \
                    hb[ri].z = fmaf(evd, wB.z, hb[ri].z); \
                    hb[ri].w = fmaf(evd, wB.w, hb[ri].w); \
                } \
            } \
        } \
        _Pragma("unroll") \
        for (int ri = 0; ri < 2; ++ri) { \
            const int row = e0 + ri; \
            float v[8] = { ha[ri].x, ha[ri].y, ha[ri].z, ha[ri].w, \
                           hb[ri].x, hb[ri].y, hb[ri].z, hb[ri].w }; \
            union { unsigned short us[8]; uint4 qv; } Hh, Hl; \
            _Pragma("unroll") \
            for (int j = 0; j < 8; ++j) { \
                const float f = fmaxf(v[j], 0.f); \
                const unsigned short h = bf16u(f); \
                Hh.us[j] = h; \
                Hl.us[j] = bf16u(f - bf16tof(h)); \
            } \
            const int boff = (cg * 16) ^ (swzk(row) << 4); \
            *(uint4*)(h1hi + (BUF) * 8192 + row * 256 + boff) = Hh.qv; \
            *(uint4*)(h1lo + (BUF) * 8192 + row * 256 + boff) = Hl.qv; \
        } \
    } while (0)

    LAYER1(0);

    // prefetch ea(1)/xw(1); load idx(3); write eaL[1]
    if (gth) {
        const int r = srowL[1 * EPB + em], c = scolL[1 * EPB + em];
        pA = ((const float4*)(eattr + ((size_t)r * NN + c) * ED))[q];
    }
    #pragma unroll
    for (int ri = 0; ri < 2; ++ri) {
        const int row = srowL[1 * EPB + e0 + ri];
        const float4* p = (const float4*)(xw1b + (size_t)row * OC + c0);
        xa[ri] = p[0]; xb[ri] = p[1];
    }
    int2 pidx;
    {
        const int ib = (3 < nper) ? 3 : (nper - 1);
        pidx = (t < EPB) ? csr[(size_t)(ibb + ib) * EPB + t] : make_int2(0, 0);
    }
    if (gth) eaL[1 * 128 + ((em * 4 + q) ^ esz)] = pA;
    BAR();   // h1[0], eaL[1], idx bufs visible

    for (int ii = 0; ii < nper; ++ii) {
        const int cb2 = ii & 1;             // h1/eaL buffer of batch ii
        const int nb  = (ii + 1) & 1;
        const int ib4 = ii & 3;             // idx buffer of batch ii

        // ---- PhaseA(ii+1): layer-1 -> h1[nb] (VALU; overlaps MFMA below)
        if (ii + 1 < nper) LAYER1(nb);

        // ---- prefetch ea/xw(ii+2) from idx buf (ii+2)&3 (barrier-crossed)
        {
            const int jb = (ii + 2) & 3;
            if (gth) {
                const int r = srowL[jb * EPB + em], c = scolL[jb * EPB + em];
                pA = ((const float4*)(eattr + ((size_t)r * NN + c) * ED))[q];
            }
            #pragma unroll
            for (int ri = 0; ri < 2; ++ri) {
                const int row = srowL[jb * EPB + e0 + ri];
                const float4* p = (const float4*)(xw1b + (size_t)row * OC + c0);
                xa[ri] = p[0]; xb[ri] = p[1];
            }
        }
        // idx(ii+3) -> LDS buf (ii+3)&3; load idx(ii+4)
        if (t < EPB) {
            srowL[((ii + 3) & 3) * EPB + t] = pidx.x;
            scolL[((ii + 3) & 3) * EPB + t] = pidx.y;
        }
        {
            const int ib = (ii + 4 < nper) ? (ii + 4) : (nper - 1);
            pidx = (t < EPB) ? csr[(size_t)(ibb + ib) * EPB + t] : make_int2(0, 0);
        }

        // ---- PhaseB(ii): 24 MFMA from h1[cb2] + epilogue -> lacc --------
        f32x16 acc = (f32x16)(0.0f);
        #pragma unroll
        for (int s = 0; s < 8; ++s) {
            const int kb = s * 32 + hi * 16;
            const bf16x8 aH = *(const bf16x8*)(h1hi + cb2 * 8192 + arow * 256 + (kb ^ ak));
            const bf16x8 aL = *(const bf16x8*)(h1lo + cb2 * 8192 + arow * 256 + (kb ^ ak));
            acc = __builtin_amdgcn_mfma_f32_32x32x16_bf16(aH, w2h[s], acc, 0, 0, 0);
            acc = __builtin_amdgcn_mfma_f32_32x32x16_bf16(aL, w2h[s], acc, 0, 0, 0);
            acc = __builtin_amdgcn_mfma_f32_32x32x16_bf16(aH, w2l[s], acc, 0, 0, 0);
        }
        // epilogue: C col=lane&31, row=(reg&3)+8*(reg>>2)+4*hi; run-combine
        #pragma unroll
        for (int g = 0; g < 4; ++g) {
            const int eb = 4 * hi + 8 * g;
            float sv = fmaxf(acc[4 * g] + b2s, 0.f);
            int ccur = scolL[ib4 * EPB + eb];
            #pragma unroll
            for (int j = 1; j < 4; ++j) {
                const float v = fmaxf(acc[4 * g + j] + b2s, 0.f);
                const int c = scolL[ib4 * EPB + eb + j];
                if (c == ccur) {
                    sv += v;
                } else {
                    const int slot = ccur - colbase0;
                    if (slot < NSLOT) {
                        if (sv != 0.f) atomicAdd(&lacc[slot * OC + c2], sv);
                    } else {
                        if (sv != 0.f) atomicAdd(&out[(size_t)ccur * OC + c2], sv);
                    }
                    ccur = c; sv = v;
                }
            }
            const int slot = ccur - colbase0;
            if (slot < NSLOT) {
                if (sv != 0.f) atomicAdd(&lacc[slot * OC + c2], sv);
            } else {
                if (sv != 0.f) atomicAdd(&out[(size_t)ccur * OC + c2], sv);
            }
        }
        // eaL(ii+2) <- prefetched regs (vmcnt naturally waits here)
        if (gth) eaL[cb2 * 128 + ((em * 4 + q) ^ esz)] = pA;
        BAR();   // h1[nb], eaL(ii+2), idx(ii+3), lacc(ii) all visible
    }

    // ---- single block-end flush (interior cols: plain store) -----------
    const int blk_e0 = ibb * EPB;
    const int blk_e1 = blk_e0 + nper * EPB;
    #pragma unroll 1
    for (int s = 0; s < NSLOT; ++s) {
        const int c = colbase0 + s;
        if (c >= NN) break;
        const int cs = colstart[c];
        const int ce = colstart[c + 1];
        if (ce <= blk_e0 || cs >= blk_e1) continue;
        if (t < OC) {
            const float v = lacc[s * OC + t];
            if (cs >= blk_e0 && ce <= blk_e1) {
                out[(size_t)c * OC + t] = v;
            } else if (v != 0.f) {
                atomicAdd(&out[(size_t)c * OC + t], v);
            }
        }
    }
    #undef LAYER1
}

#define LDS_BYTES 54272

extern "C" void kernel_launch(void* const* d_in, const int* in_sizes, int n_in,
                              void* d_out, int out_size, void* d_ws, size_t ws_size,
                              hipStream_t stream) {
    const float* x    = (const float*)d_in[0];
    const int*   eidx = (const int*)d_in[1];
    const float* ea   = (const float*)d_in[2];
    const float* W1   = (const float*)d_in[3];
    const float* b1   = (const float*)d_in[4];
    const float* W2   = (const float*)d_in[5];
    const float* b2   = (const float*)d_in[6];
    float* out = (float*)d_out;

    const int E = in_sizes[1] / 2;

    char* ws = (char*)d_ws;
    float* xw1b     = (float*)ws;                        // 2 MB
    int*   hist8    = (int*)(ws + 2097152);              // 128 KB
    int*   cursor8  = (int*)(ws + 2097152 + 131072);     // 128 KB
    int*   colstart = (int*)(ws + 2097152 + 262144);     // 16.4 KB
    int*   binloc   = (int*)(ws + 2097152 + 294912);     // 16 KB
    int*   blocksum = (int*)(ws + 2097152 + 311296);     // 64 B
    int2*  csr      = (int2*)(ws + 2097152 + 327680);    // 2 MB

    hipMemsetAsync(hist8, 0, 131072, stream);
    k_xw1<<<NN / 8, 128, 0, stream>>>(x, W1, b1, eidx, xw1b, out, hist8, E);
    k_scanA<<<16, 256, 0, stream>>>(hist8, binloc, blocksum);
    k_scanB<<<16, 256, 0, stream>>>(hist8, binloc, blocksum, cursor8, colstart, E);
    k_scatter<<<(E + 255) / 256, 256, 0, stream>>>(eidx, cursor8, csr, E);

    hipFuncSetAttribute(reinterpret_cast<const void*>(k_edge11),
                        hipFuncAttributeMaxDynamicSharedMemorySize, LDS_BYTES);
    k_edge11<<<NBLK, NT, LDS_BYTES, stream>>>(csr, ea, xw1b, W1, W2, b2,
                                              colstart, out, E);
}